// Round 15
// baseline (66.879 us; speedup 1.0000x reference)
//
#include <hip/hip_runtime.h>
#include <hip/hip_bf16.h>

// SimpleGATLayer fused kernel set for MI355X (gfx950).
// B=8, N=2048, F=U=128 (hard-coded from reference setup).
//
//  k_h    : W->LDS transpose + H = X@W via MFMA -> HT(b,u,n) bf16, s, t
//  k_attn : fused masked softmax(leaky(s_i+t_j)) @ H, relu, f32 out.
//           Round 15: BARRIER-FREE loop. No LDS staging — each wave reads
//           its B-fragments directly from global (L2/L1-resident HT,
//           16B/lane contiguous). Waves run completely independently; the
//           only sync is one __syncthreads before the final j-quarter
//           combine. Keeps: 32 rows/wave (16 MFMA per 8 loads), fixed-scale
//           softmax, depth-2 A/t register prefetch, b-per-XCD pinning,
//           rot-phase alignment of co-resident blocks for L1 reuse.

#define NEG_INF -1.0e9f

typedef __bf16 bf16x8 __attribute__((ext_vector_type(8)));
typedef unsigned short ushort8 __attribute__((ext_vector_type(8)));
typedef float f32x4 __attribute__((ext_vector_type(4)));

__device__ __forceinline__ unsigned short f2b(float x) {
    // f32 -> bf16 round-to-nearest-even
    unsigned u = __builtin_bit_cast(unsigned, x);
    u += 0x7fffu + ((u >> 16) & 1u);
    return (unsigned short)(u >> 16);
}

// ---------------- K1: H = X@W, plus s,t and HT (W transposed in-kernel) ----
// grid = 256 blocks x 256 thr; each wave computes 16 rows x 128 u.
__global__ __launch_bounds__(256) void k_h(const float* __restrict__ X,
                                           const float* __restrict__ W,
                                           const float* __restrict__ a,
                                           unsigned short* __restrict__ HT,
                                           float* __restrict__ sbuf,
                                           float* __restrict__ tbuf) {
    __shared__ unsigned short WT[128 * 136];   // padded stride: bank spread

    const int tid  = threadIdx.x;
    const int w    = tid >> 6;
    const int lane = tid & 63;
    const int r    = lane & 15;     // MFMA row/col index
    const int cg   = lane >> 4;     // k-group 0..3

    // cooperative W transpose: WT[u][f] = bf16(W[f][u])
    for (int i = tid; i < 16384; i += 256) {
        int u = i >> 7, f = i & 127;
        WT[u * 136 + f] = f2b(W[f * 128 + u]);
    }
    __syncthreads();

    const int row0 = blockIdx.x * 64 + w * 16;  // flattened (b*2048+n) row
    const int b    = row0 >> 11;
    const int n0   = row0 & 2047;
    const int arow = row0 + r;

    f32x4 acc[8] = {};

#pragma unroll
    for (int k0 = 0; k0 < 128; k0 += 32) {
        const float* xp = X + (size_t)arow * 128 + k0 + cg * 8;
        ushort8 xa;
#pragma unroll
        for (int j = 0; j < 8; j++) xa[j] = f2b(xp[j]);
        bf16x8 av = __builtin_bit_cast(bf16x8, xa);
#pragma unroll
        for (int ut = 0; ut < 8; ut++) {
            ushort8 wb = *(const ushort8*)(&WT[(ut * 16 + r) * 136 + k0 + cg * 8]);
            acc[ut] = __builtin_amdgcn_mfma_f32_16x16x32_bf16(
                av, __builtin_bit_cast(bf16x8, wb), acc[ut], 0, 0, 0);
        }
    }

    // D layout: lane holds H[row0 + cg*4 + reg][ut*16 + r]
    float sp[4] = {0.f, 0.f, 0.f, 0.f};
    float tp[4] = {0.f, 0.f, 0.f, 0.f};
#pragma unroll
    for (int ut = 0; ut < 8; ut++) {
        int u = ut * 16 + r;
        float as = a[u];
        float ad = a[128 + u];
#pragma unroll
        for (int reg = 0; reg < 4; reg++) {
            float h = acc[ut][reg];
            int nrow = n0 + cg * 4 + reg;
            HT[((size_t)b * 128 + u) * 2048 + nrow] = f2b(h);
            sp[reg] += h * as;
            tp[reg] += h * ad;
        }
    }
#pragma unroll
    for (int msk = 1; msk < 16; msk <<= 1) {
#pragma unroll
        for (int reg = 0; reg < 4; reg++) {
            sp[reg] += __shfl_xor(sp[reg], msk);
            tp[reg] += __shfl_xor(tp[reg], msk);
        }
    }
    if (r == 0) {
#pragma unroll
        for (int reg = 0; reg < 4; reg++) {
            int row = row0 + cg * 4 + reg;
            sbuf[row] = sp[reg];
            tbuf[row] = tp[reg];
        }
    }
}

// ---------------- K2: fused masked-softmax attention @ H ----------------
// grid = 512 blocks (2/CU), block = 256 thr (4 waves, one per j-quarter).
// Block: 32 i-rows x 128 u of batch b = bid&7. Wave jq owns all 32 rows
// (two A-fragments: rows r, r+16) x its 512-j quarter (16 tiles of 32).
// Loop: NO barriers, NO LDS. B-fragments read directly from global HT
// (16B/lane, L2/L1-resident; co-resident block walks same rot phase ->
// L1 hits). A/t depth-2 register prefetch. Fixed-scale softmax p=exp(e-16).
// One __syncthreads before the cross-quarter combine.
__global__ __launch_bounds__(256, 2) void k_attn(const int* __restrict__ A,
                                                 const unsigned short* __restrict__ HT,
                                                 const float* __restrict__ sbuf,
                                                 const float* __restrict__ tbuf,
                                                 float* __restrict__ out) {
    __shared__ float accS[3 * 32 * 132];   // 50.7 KB (combine only)
    __shared__ float dSm[4][32];

    const int tid  = threadIdx.x;
    const int jq   = tid >> 6;          // 0..3 j-quarter (512 j)
    const int lane = tid & 63;
    const int r    = lane & 15;
    const int cg   = lane >> 4;
    const int bid  = blockIdx.x;
    const int b    = bid & 7;           // batch pinned per XCD
    const int it   = bid >> 3;          // 0..63 i-tile
    const int i0   = it * 32;
    const int rot  = it & 15;           // tile-order rotation; co-resident
                                        // block (bid+256) has the same rot

    const int irow0 = i0 + r;           // row group 0; group 1 = +16
    const float s0 = sbuf[b * 2048 + irow0];
    const float s1 = sbuf[b * 2048 + irow0 + 16];
    const unsigned short* Hb = HT + ((size_t)b * 128) * 2048 + jq * 512;
    const unsigned short* Hrow = Hb + (size_t)r * 2048;   // + ut*16*2048 + jb
    const int*   Aq0 = A    + ((size_t)(b * 2048 + irow0)) * 2048 + jq * 512 + cg * 8;
    const int*   Aq1 = Aq0 + 16 * 2048;
    const float* Tq  = tbuf + (size_t)b * 2048 + jq * 512 + cg * 8;

    f32x4 acc0[8] = {};
    f32x4 acc1[8] = {};
    float den0 = 0.f, den1 = 0.f;

    // ---- prologue: A/t tiles 0,1 into regs ----
    int4   aP0[2][2], aP1[2][2];   // slot k&1; static indices (full unroll)
    float4 tP[2][2];
    {
        const int j0 = rot * 32;
        const int j1 = ((1 + rot) & 15) * 32;
        aP0[0][0] = *(const int4*)(Aq0 + j0);
        aP0[0][1] = *(const int4*)(Aq0 + j0 + 4);
        aP1[0][0] = *(const int4*)(Aq1 + j0);
        aP1[0][1] = *(const int4*)(Aq1 + j0 + 4);
        tP[0][0]  = *(const float4*)(Tq + j0);
        tP[0][1]  = *(const float4*)(Tq + j0 + 4);
        aP0[1][0] = *(const int4*)(Aq0 + j1);
        aP0[1][1] = *(const int4*)(Aq0 + j1 + 4);
        aP1[1][0] = *(const int4*)(Aq1 + j1);
        aP1[1][1] = *(const int4*)(Aq1 + j1 + 4);
        tP[1][0]  = *(const float4*)(Tq + j1);
        tP[1][1]  = *(const float4*)(Tq + j1 + 4);
    }

#pragma unroll
    for (int k = 0; k < 16; ++k) {
        const int p = k & 1;
        const int jb = ((k + rot) & 15) * 32 + cg * 8;

        // consume slot (register copies), then refill with tile k+2
        int4   ca0 = aP0[p][0], ca1 = aP0[p][1];
        int4   cb0 = aP1[p][0], cb1 = aP1[p][1];
        float4 ct0 = tP[p][0],  ct1 = tP[p][1];
        if (k < 14) {
            const int ja = ((k + 2 + rot) & 15) * 32;
            aP0[p][0] = *(const int4*)(Aq0 + ja);
            aP0[p][1] = *(const int4*)(Aq0 + ja + 4);
            aP1[p][0] = *(const int4*)(Aq1 + ja);
            aP1[p][1] = *(const int4*)(Aq1 + ja + 4);
            tP[p][0]  = *(const float4*)(Tq + ja);
            tP[p][1]  = *(const float4*)(Tq + ja + 4);
        }

        // ---- B fragments: direct global loads (8 x 16B/lane, independent) ----
        ushort8 hbv[8];
#pragma unroll
        for (int ut = 0; ut < 8; ut++)
            hbv[ut] = *(const ushort8*)(Hrow + (size_t)(ut * 16) * 2048 + jb);

        // ---- P fragments for both row groups (t shared) ----
        float tv[8] = {ct0.x, ct0.y, ct0.z, ct0.w, ct1.x, ct1.y, ct1.z, ct1.w};
        int   a0i[8] = {ca0.x, ca0.y, ca0.z, ca0.w, ca1.x, ca1.y, ca1.z, ca1.w};
        int   a1i[8] = {cb0.x, cb0.y, cb0.z, cb0.w, cb1.x, cb1.y, cb1.z, cb1.w};
        bf16x8 pa0, pa1;
#pragma unroll
        for (int jj = 0; jj < 8; jj++) {
            float x0 = s0 + tv[jj];
            float e0 = fmaxf(x0, 0.2f * x0);
            float p0 = __expf(e0 - 16.0f);
            p0 = a0i[jj] > 0 ? p0 : 0.f;
            den0 += p0;
            pa0[jj] = (__bf16)p0;

            float x1 = s1 + tv[jj];
            float e1 = fmaxf(x1, 0.2f * x1);
            float p1 = __expf(e1 - 16.0f);
            p1 = a1i[jj] > 0 ? p1 : 0.f;
            den1 += p1;
            pa1[jj] = (__bf16)p1;
        }

        // ---- 16 MFMA per 8 B-loads (B shared by both row groups) ----
#pragma unroll
        for (int ut = 0; ut < 8; ut++) {
            bf16x8 hb = __builtin_bit_cast(bf16x8, hbv[ut]);
            acc0[ut] = __builtin_amdgcn_mfma_f32_16x16x32_bf16(pa0, hb, acc0[ut], 0, 0, 0);
            acc1[ut] = __builtin_amdgcn_mfma_f32_16x16x32_bf16(pa1, hb, acc1[ut], 0, 0, 0);
        }
    }

    // per-wave denominators per row (sum over the 4 cg k-groups)
    den0 += __shfl_xor(den0, 16);
    den0 += __shfl_xor(den0, 32);
    den1 += __shfl_xor(den1, 16);
    den1 += __shfl_xor(den1, 32);

    if (cg == 0) { dSm[jq][r] = den0; dSm[jq][16 + r] = den1; }
    if (jq != 0) {
        const int base = (jq - 1) * 32;
#pragma unroll
        for (int ut = 0; ut < 8; ut++)
#pragma unroll
            for (int reg = 0; reg < 4; reg++) {
                accS[(base + cg * 4 + reg) * 132 + ut * 16 + r]      = acc0[ut][reg];
                accS[(base + 16 + cg * 4 + reg) * 132 + ut * 16 + r] = acc1[ut][reg];
            }
    }
    __syncthreads();
    if (jq == 0) {
        float dinv0[4], dinv1[4];
#pragma unroll
        for (int reg = 0; reg < 4; reg++) {
            const int row0_ = cg * 4 + reg;
            const int row1_ = 16 + cg * 4 + reg;
            dinv0[reg] = 1.0f / (dSm[0][row0_] + dSm[1][row0_] +
                                 dSm[2][row0_] + dSm[3][row0_]);
            dinv1[reg] = 1.0f / (dSm[0][row1_] + dSm[1][row1_] +
                                 dSm[2][row1_] + dSm[3][row1_]);
        }
#pragma unroll
        for (int ut = 0; ut < 8; ut++) {
#pragma unroll
            for (int reg = 0; reg < 4; reg++) {
                const int lr0 = cg * 4 + reg;
                const int lr1 = 16 + cg * 4 + reg;
                float n0 = acc0[ut][reg]
                         + accS[(0 * 32 + lr0) * 132 + ut * 16 + r]
                         + accS[(1 * 32 + lr0) * 132 + ut * 16 + r]
                         + accS[(2 * 32 + lr0) * 132 + ut * 16 + r];
                float n1 = acc1[ut][reg]
                         + accS[(0 * 32 + lr1) * 132 + ut * 16 + r]
                         + accS[(1 * 32 + lr1) * 132 + ut * 16 + r]
                         + accS[(2 * 32 + lr1) * 132 + ut * 16 + r];
                out[((size_t)(b * 2048 + i0 + lr0)) * 128 + ut * 16 + r] =
                    fmaxf(n0 * dinv0[reg], 0.f);
                out[((size_t)(b * 2048 + i0 + lr1)) * 128 + ut * 16 + r] =
                    fmaxf(n1 * dinv1[reg], 0.f);
            }
        }
    }
}

extern "C" void kernel_launch(void* const* d_in, const int* in_sizes, int n_in,
                              void* d_out, int out_size, void* d_ws, size_t ws_size,
                              hipStream_t stream) {
    const float* X = (const float*)d_in[0];   // (8,2048,128) f32
    const int*   A = (const int*)d_in[1];     // (8,2048,2048) i32
    const float* W = (const float*)d_in[2];   // (128,128) f32
    const float* a = (const float*)d_in[3];   // (256,1) f32
    float* out = (float*)d_out;               // (8,2048,128) f32

    char* ws = (char*)d_ws;
    float*          sb  = (float*)(ws);                           // 64 KB
    float*          tb  = (float*)(ws + 65536);                   // 64 KB
    unsigned short* HT  = (unsigned short*)(ws + 131072);         // 4 MB

    k_h<<<dim3(256), dim3(256), 0, stream>>>(X, W, a, HT, sb, tb);
    k_attn<<<dim3(512), dim3(256), 0, stream>>>(A, HT, sb, tb, out);
}

// Round 16
// 58.617 us; speedup vs baseline: 1.1410x; 1.1410x over previous
//
#include <hip/hip_runtime.h>
#include <hip/hip_bf16.h>

// SimpleGATLayer fused kernel set for MI355X (gfx950).
// B=8, N=2048, F=U=128 (hard-coded from reference setup).
//
//  k_h    : W->LDS transpose + H = X@W via MFMA -> HT(b,u,n) bf16, s, t
//  k_attn : fused masked softmax(leaky(s_i+t_j)) @ H, relu, f32 out.
//           Round 16: deep A-prefetch. vmcnt retires IN ORDER, so any wait
//           for same/previous-iteration loads also waits for the contended
//           L3 A-stream (the invariant ~2000cy/iter stall across R10-R15).
//           Fix: depth-3 A/t ring (3-iteration flight) + stage issued FIRST
//           (sched_barrier pins order) so the stage wait never drains the
//           newest A group. Wait ladder: vmcnt(16)/10/4/0.

#define NEG_INF -1.0e9f

typedef __bf16 bf16x8 __attribute__((ext_vector_type(8)));
typedef unsigned short ushort8 __attribute__((ext_vector_type(8)));
typedef float f32x4 __attribute__((ext_vector_type(4)));

__device__ __forceinline__ unsigned short f2b(float x) {
    // f32 -> bf16 round-to-nearest-even
    unsigned u = __builtin_bit_cast(unsigned, x);
    u += 0x7fffu + ((u >> 16) & 1u);
    return (unsigned short)(u >> 16);
}

__device__ __forceinline__ void gload_lds16(const void* g, void* l) {
    __builtin_amdgcn_global_load_lds(
        (const __attribute__((address_space(1))) void*)g,
        (__attribute__((address_space(3))) void*)l, 16, 0, 0);
}

// ---------------- K1: H = X@W, plus s,t and HT (W transposed in-kernel) ----
// grid = 256 blocks x 256 thr; each wave computes 16 rows x 128 u.
__global__ __launch_bounds__(256) void k_h(const float* __restrict__ X,
                                           const float* __restrict__ W,
                                           const float* __restrict__ a,
                                           unsigned short* __restrict__ HT,
                                           float* __restrict__ sbuf,
                                           float* __restrict__ tbuf) {
    __shared__ unsigned short WT[128 * 136];   // padded stride: bank spread

    const int tid  = threadIdx.x;
    const int w    = tid >> 6;
    const int lane = tid & 63;
    const int r    = lane & 15;     // MFMA row/col index
    const int cg   = lane >> 4;     // k-group 0..3

    // cooperative W transpose: WT[u][f] = bf16(W[f][u])
    for (int i = tid; i < 16384; i += 256) {
        int u = i >> 7, f = i & 127;
        WT[u * 136 + f] = f2b(W[f * 128 + u]);
    }
    __syncthreads();

    const int row0 = blockIdx.x * 64 + w * 16;  // flattened (b*2048+n) row
    const int b    = row0 >> 11;
    const int n0   = row0 & 2047;
    const int arow = row0 + r;

    f32x4 acc[8] = {};

#pragma unroll
    for (int k0 = 0; k0 < 128; k0 += 32) {
        const float* xp = X + (size_t)arow * 128 + k0 + cg * 8;
        ushort8 xa;
#pragma unroll
        for (int j = 0; j < 8; j++) xa[j] = f2b(xp[j]);
        bf16x8 av = __builtin_bit_cast(bf16x8, xa);
#pragma unroll
        for (int ut = 0; ut < 8; ut++) {
            ushort8 wb = *(const ushort8*)(&WT[(ut * 16 + r) * 136 + k0 + cg * 8]);
            acc[ut] = __builtin_amdgcn_mfma_f32_16x16x32_bf16(
                av, __builtin_bit_cast(bf16x8, wb), acc[ut], 0, 0, 0);
        }
    }

    // D layout: lane holds H[row0 + cg*4 + reg][ut*16 + r]
    float sp[4] = {0.f, 0.f, 0.f, 0.f};
    float tp[4] = {0.f, 0.f, 0.f, 0.f};
#pragma unroll
    for (int ut = 0; ut < 8; ut++) {
        int u = ut * 16 + r;
        float as = a[u];
        float ad = a[128 + u];
#pragma unroll
        for (int reg = 0; reg < 4; reg++) {
            float h = acc[ut][reg];
            int nrow = n0 + cg * 4 + reg;
            HT[((size_t)b * 128 + u) * 2048 + nrow] = f2b(h);
            sp[reg] += h * as;
            tp[reg] += h * ad;
        }
    }
#pragma unroll
    for (int msk = 1; msk < 16; msk <<= 1) {
#pragma unroll
        for (int reg = 0; reg < 4; reg++) {
            sp[reg] += __shfl_xor(sp[reg], msk);
            tp[reg] += __shfl_xor(tp[reg], msk);
        }
    }
    if (r == 0) {
#pragma unroll
        for (int reg = 0; reg < 4; reg++) {
            int row = row0 + cg * 4 + reg;
            sbuf[row] = sp[reg];
            tbuf[row] = tp[reg];
        }
    }
}

// ---------------- K2: fused masked-softmax attention @ H ----------------
// grid = 256 blocks (1/CU), block = 512 thr (8 waves).
// Block: 64 i-rows x 128 u of batch b = bid&7. Wave (jq = w>>1, g = w&1):
// rows [i0+g*32, +32) as two A-fragments (r, r+16), j-quarter jq (512 j,
// 16 tiles of 32). Staged HT quarter-tile shared by 2 waves (each stages
// its u-half, 4 gload_lds). Depth-3 A/t register ring -> A-loads get a
// 3-iteration flight; stage issued BEFORE A each iteration so the stage
// wait (vmcnt(16)) never drains the newest A group (in-order retirement).
__global__ __launch_bounds__(512) void k_attn(const int* __restrict__ A,
                                              const unsigned short* __restrict__ HT,
                                              const float* __restrict__ sbuf,
                                              const float* __restrict__ tbuf,
                                              float* __restrict__ out) {
    __shared__ char smem[65536];        // stage: [jq][p][8KB]; reused for combine
    __shared__ float dSm[4][64];

    const int tid  = threadIdx.x;
    const int w    = tid >> 6;          // 0..7
    const int lane = tid & 63;
    const int r    = lane & 15;
    const int cg   = lane >> 4;
    const int jq   = w >> 1;            // j-quarter (512 j)
    const int g    = w & 1;             // row-group (32 rows)
    const int bid  = blockIdx.x;
    const int b    = bid & 7;           // batch pinned per XCD
    const int it   = bid >> 3;          // 0..31 i-tile
    const int i0   = it * 64;
    const int rot  = it & 15;           // per-block j-tile rotation

    const int irow0 = i0 + g * 32 + r;  // row group rows: irow0, irow0+16
    const float s0 = sbuf[b * 2048 + irow0];
    const float s1 = sbuf[b * 2048 + irow0 + 16];
    const unsigned short* Hb = HT + ((size_t)b * 128) * 2048 + jq * 512;
    const int*   Aq0 = A    + ((size_t)(b * 2048 + irow0)) * 2048 + jq * 512 + cg * 8;
    const int*   Aq1 = Aq0 + 16 * 2048;
    const float* Tq  = tbuf + (size_t)b * 2048 + jq * 512 + cg * 8;

    // staging geometry: wave stages u-rows [g*64,(g+1)*64) (4 instrs x 16).
    // LDS tile = 128 rows x 64B (4 chunks of 16B); chunk hash f(row) =
    // (row&3)^((row>>2)&3), applied via global src on write and on read.
    const int srow = (lane >> 2);
    const int csrc = (lane & 3) ^ ((lane >> 2) & 3) ^ ((lane >> 4) & 3);
    char* const qbase = smem + jq * 16384;            // this quarter's 2 buffers
    const unsigned short* src0 = Hb + (size_t)(g * 64 + srow) * 2048 + csrc * 8;
    const int rsl = ((r & 3) ^ ((r >> 2) & 3));       // read-side hash base

    f32x4 acc0[8] = {};
    f32x4 acc1[8] = {};
    float den0 = 0.f, den1 = 0.f;

    // ---- prologue: stage HT tile 0; A/t tiles 0,1,2 into ring slots ----
    int4   aP0[3][2], aP1[3][2];   // ring slot = k % 3 (static under unroll)
    float4 tP[3][2];
    {
        const int j0 = rot * 32;
#pragma unroll
        for (int i = 0; i < 4; i++)
            gload_lds16(src0 + (size_t)i * 16 * 2048 + j0,
                        qbase + (g * 4 + i) * 1024);
#pragma unroll
        for (int q = 0; q < 3; ++q) {
            const int jp = ((q + rot) & 15) * 32;
            aP0[q][0] = *(const int4*)(Aq0 + jp);
            aP0[q][1] = *(const int4*)(Aq0 + jp + 4);
            aP1[q][0] = *(const int4*)(Aq1 + jp);
            aP1[q][1] = *(const int4*)(Aq1 + jp + 4);
            tP[q][0]  = *(const float4*)(Tq + jp);
            tP[q][1]  = *(const float4*)(Tq + jp + 4);
        }
    }
    __syncthreads();   // full drain once: A/t(0..2) + stage0 ready

#pragma unroll
    for (int k = 0; k < 16; ++k) {
        const int p  = k & 1;
        const int sl = k % 3;           // compile-time (full unroll)

        // consume ring slot (register copies), slot is then free for k+3
        int4   ca0 = aP0[sl][0], ca1 = aP0[sl][1];
        int4   cb0 = aP1[sl][0], cb1 = aP1[sl][1];
        float4 ct0 = tP[sl][0],  ct1 = tP[sl][1];

        // ---- issue stage(k+1) FIRST (older in the in-order vm queue) ----
        if (k < 15) {
            const int jn = ((k + 1 + rot) & 15) * 32;
            char* dst = qbase + (p ^ 1) * 8192;
#pragma unroll
            for (int i = 0; i < 4; i++)
                gload_lds16(src0 + (size_t)i * 16 * 2048 + jn,
                            dst + (g * 4 + i) * 1024);
        }
        __builtin_amdgcn_sched_barrier(0);   // pin issue order: stage < A
        // ---- issue A/t(k+3) into ring slot (3-iteration flight) ----
        if (k < 13) {
            const int ja = ((k + 3 + rot) & 15) * 32;
            aP0[sl][0] = *(const int4*)(Aq0 + ja);
            aP0[sl][1] = *(const int4*)(Aq0 + ja + 4);
            aP1[sl][0] = *(const int4*)(Aq1 + ja);
            aP1[sl][1] = *(const int4*)(Aq1 + ja + 4);
            tP[sl][0]  = *(const float4*)(Tq + ja);
            tP[sl][1]  = *(const float4*)(Tq + ja + 4);
        }

        // ---- P fragments for both row groups (t shared) ----
        float tv[8] = {ct0.x, ct0.y, ct0.z, ct0.w, ct1.x, ct1.y, ct1.z, ct1.w};
        int   a0i[8] = {ca0.x, ca0.y, ca0.z, ca0.w, ca1.x, ca1.y, ca1.z, ca1.w};
        int   a1i[8] = {cb0.x, cb0.y, cb0.z, cb0.w, cb1.x, cb1.y, cb1.z, cb1.w};
        bf16x8 pa0, pa1;
#pragma unroll
        for (int jj = 0; jj < 8; jj++) {
            float x0 = s0 + tv[jj];
            float e0 = fmaxf(x0, 0.2f * x0);
            float p0 = __expf(e0 - 16.0f);
            p0 = a0i[jj] > 0 ? p0 : 0.f;
            den0 += p0;
            pa0[jj] = (__bf16)p0;

            float x1 = s1 + tv[jj];
            float e1 = fmaxf(x1, 0.2f * x1);
            float p1 = __expf(e1 - 16.0f);
            p1 = a1i[jj] > 0 ? p1 : 0.f;
            den1 += p1;
            pa1[jj] = (__bf16)p1;
        }

        // ---- wait ladder (in-order queue: [A(k+2), S(k+1), A(k+3)] may
        // stay in flight = 16; only older groups — incl. S(k) — drain).
        if (k < 13)       asm volatile("s_waitcnt vmcnt(16)" ::: "memory");
        else if (k == 13) asm volatile("s_waitcnt vmcnt(10)" ::: "memory");
        else if (k == 14) asm volatile("s_waitcnt vmcnt(4)"  ::: "memory");
        else              asm volatile("s_waitcnt vmcnt(0)"  ::: "memory");
        __builtin_amdgcn_s_barrier();
        __builtin_amdgcn_sched_barrier(0);   // no ds_read hoisting (rule #18)

        // ---- B fragments from staged LDS tile: 8 ds_read, 16 MFMA ----
        const char* buf = qbase + p * 8192;
#pragma unroll
        for (int ut = 0; ut < 8; ut++) {
            ushort8 hb = *(const ushort8*)(buf + (ut * 16 + r) * 64 +
                                           ((cg ^ rsl) * 16));
            bf16x8 hbv = __builtin_bit_cast(bf16x8, hb);
            acc0[ut] = __builtin_amdgcn_mfma_f32_16x16x32_bf16(pa0, hbv, acc0[ut], 0, 0, 0);
            acc1[ut] = __builtin_amdgcn_mfma_f32_16x16x32_bf16(pa1, hbv, acc1[ut], 0, 0, 0);
        }

        if (k < 15) {
            __builtin_amdgcn_s_barrier();        // WAR guard: buf p is staged
            __builtin_amdgcn_sched_barrier(0);   // into next iteration
        }
    }

    // per-wave denominators per row (sum over the 4 cg k-groups)
    den0 += __shfl_xor(den0, 16);
    den0 += __shfl_xor(den0, 32);
    den1 += __shfl_xor(den1, 16);
    den1 += __shfl_xor(den1, 32);

    __syncthreads();   // everyone done with stage buffers before accS reuse

    if (cg == 0) { dSm[jq][g * 32 + r] = den0; dSm[jq][g * 32 + 16 + r] = den1; }

    // ---- combine the 4 j-quarters in two row-group passes (smem reuse) ----
    // accS holds quarters 1..3 of one row-group: 3 x 32 x 132 f32 = 50.7 KB.
    float* accS = (float*)smem;
#pragma unroll
    for (int gg = 0; gg < 2; ++gg) {
        __syncthreads();
        if (g == gg && jq != 0) {
            const int base = (jq - 1) * 32;
#pragma unroll
            for (int ut = 0; ut < 8; ut++)
#pragma unroll
                for (int reg = 0; reg < 4; reg++) {
                    accS[(base + cg * 4 + reg) * 132 + ut * 16 + r]      = acc0[ut][reg];
                    accS[(base + 16 + cg * 4 + reg) * 132 + ut * 16 + r] = acc1[ut][reg];
                }
        }
        __syncthreads();
        if (g == gg && jq == 0) {
            float dinv0[4], dinv1[4];
#pragma unroll
            for (int reg = 0; reg < 4; reg++) {
                const int row0_ = gg * 32 + cg * 4 + reg;
                const int row1_ = gg * 32 + 16 + cg * 4 + reg;
                dinv0[reg] = 1.0f / (dSm[0][row0_] + dSm[1][row0_] +
                                     dSm[2][row0_] + dSm[3][row0_]);
                dinv1[reg] = 1.0f / (dSm[0][row1_] + dSm[1][row1_] +
                                     dSm[2][row1_] + dSm[3][row1_]);
            }
#pragma unroll
            for (int ut = 0; ut < 8; ut++) {
#pragma unroll
                for (int reg = 0; reg < 4; reg++) {
                    const int lr0 = cg * 4 + reg;        // within group
                    const int lr1 = 16 + cg * 4 + reg;
                    float n0 = acc0[ut][reg]
                             + accS[(0 * 32 + lr0) * 132 + ut * 16 + r]
                             + accS[(1 * 32 + lr0) * 132 + ut * 16 + r]
                             + accS[(2 * 32 + lr0) * 132 + ut * 16 + r];
                    float n1 = acc1[ut][reg]
                             + accS[(0 * 32 + lr1) * 132 + ut * 16 + r]
                             + accS[(1 * 32 + lr1) * 132 + ut * 16 + r]
                             + accS[(2 * 32 + lr1) * 132 + ut * 16 + r];
                    out[((size_t)(b * 2048 + i0 + gg * 32 + lr0)) * 128 +
                        ut * 16 + r] = fmaxf(n0 * dinv0[reg], 0.f);
                    out[((size_t)(b * 2048 + i0 + gg * 32 + lr1)) * 128 +
                        ut * 16 + r] = fmaxf(n1 * dinv1[reg], 0.f);
                }
            }
        }
    }
}

extern "C" void kernel_launch(void* const* d_in, const int* in_sizes, int n_in,
                              void* d_out, int out_size, void* d_ws, size_t ws_size,
                              hipStream_t stream) {
    const float* X = (const float*)d_in[0];   // (8,2048,128) f32
    const int*   A = (const int*)d_in[1];     // (8,2048,2048) i32
    const float* W = (const float*)d_in[2];   // (128,128) f32
    const float* a = (const float*)d_in[3];   // (256,1) f32
    float* out = (float*)d_out;               // (8,2048,128) f32

    char* ws = (char*)d_ws;
    float*          sb  = (float*)(ws);                           // 64 KB
    float*          tb  = (float*)(ws + 65536);                   // 64 KB
    unsigned short* HT  = (unsigned short*)(ws + 131072);         // 4 MB

    k_h<<<dim3(256), dim3(256), 0, stream>>>(X, W, a, HT, sb, tb);
    k_attn<<<dim3(256), dim3(512), 0, stream>>>(A, HT, sb, tb, out);
}